// Round 14
// baseline (2576.795 us; speedup 1.0000x reference)
//
#include <hip/hip_runtime.h>
#include <cstdint>
#include <utility>

#define NN0 80000
#define NE 1280000
#define MMB_GRID 2048
#define EB 2048          // elems per block in edge sort (NE/EB = 625 exact)
#define ENB 625
#define HSTRIDE 20480    // per-pass score-hist buffer stride (256*80 >= 256*nblk)

static inline int cdiv(int a, int b){ return (a+b-1)/b; }

// ---- FUSED conv: gather (x-space) + matmul [64,64] + BN partials ----
__global__ void k_conv64(const int* __restrict__ rp, const int* __restrict__ col,
                         const float* __restrict__ dinv, const float* __restrict__ x,
                         const float* __restrict__ W, float* __restrict__ out,
                         float* __restrict__ part, int n){
  __shared__ float yl[4][64];
  __shared__ float ls[64], lq[64];
  int lane = threadIdx.x & 63, w = threadIdx.x >> 6;
  if (threadIdx.x < 64){ ls[threadIdx.x] = 0.f; lq[threadIdx.x] = 0.f; }
  __syncthreads();
  float sa = 0.f, sq = 0.f;
  int wid = blockIdx.x*4 + w, nw = gridDim.x*4;
  for (int i = wid; i < n; i += nw){
    int beg = rp[i], end = rp[i+1];
    float di = dinv[i];
    float y = 0.f;
    int j = beg;
    for (; j + 4 <= end; j += 4){
      int s0 = col[j], s1 = col[j+1], s2 = col[j+2], s3 = col[j+3];
      float y0 = dinv[s0]*x[s0*64+lane];
      float y1 = dinv[s1]*x[s1*64+lane];
      float y2 = dinv[s2]*x[s2*64+lane];
      float y3 = dinv[s3]*x[s3*64+lane];
      y += (y0+y1) + (y2+y3);
    }
    for (; j < end; j++){ int s = col[j]; y += dinv[s]*x[s*64+lane]; }
    y = di*y + 2.f*di*di*x[i*64+lane];
    yl[w][lane] = y;
    float acc = 0.f;
    #pragma unroll
    for (int k2 = 0; k2 < 64; k2++)
      acc += yl[w][k2]*W[k2*64+lane];
    out[i*64+lane] = acc;
    sa += acc; sq += acc*acc;
  }
  atomicAdd(&ls[lane], sa); atomicAdd(&lq[lane], sq);
  __syncthreads();
  if (threadIdx.x < 128)
    part[blockIdx.x*128 + threadIdx.x] =
      (threadIdx.x < 64) ? ls[threadIdx.x] : lq[threadIdx.x-64];
}

// Fin=3 matmul (first conv), reads gathered y3 rows
__global__ void k_matmul_bn3(const float* __restrict__ x, const float* __restrict__ W,
                             float* __restrict__ h, float* __restrict__ part, int n){
  __shared__ float ls[64], lq[64];
  int f = threadIdx.x & 63;
  float sa = 0.f, sq = 0.f;
  int total = n*64, stride = gridDim.x*blockDim.x;
  for (int t = blockIdx.x*blockDim.x + threadIdx.x; t < total; t += stride){
    int i = t >> 6;
    float s = x[i*3]*W[f] + x[i*3+1]*W[64+f] + x[i*3+2]*W[128+f];
    h[t] = s; sa += s; sq += s*s;
  }
  if (threadIdx.x < 64){ ls[threadIdx.x] = 0.f; lq[threadIdx.x] = 0.f; }
  __syncthreads();
  atomicAdd(&ls[f], sa); atomicAdd(&lq[f], sq);
  __syncthreads();
  if (threadIdx.x < 128)
    part[blockIdx.x*128 + threadIdx.x] =
      (threadIdx.x < 64) ? ls[threadIdx.x] : lq[threadIdx.x-64];
}

__global__ void k_stats_reduce(const float* __restrict__ part, float* __restrict__ stats){
  int c = blockIdx.x, lane = threadIdx.x;
  float s = 0.f;
  for (int b = lane; b < MMB_GRID; b += 64) s += part[b*128 + c];
  for (int o = 32; o > 0; o >>= 1) s += __shfl_xor(s, o);
  if (lane == 0) stats[c] = s;
}

__global__ void k_matvec(const float* __restrict__ x, const float* __restrict__ W,
                         float* __restrict__ h1, int n){
  int lane = threadIdx.x & 63, w = threadIdx.x >> 6;
  int wid = blockIdx.x*4 + w, nw = gridDim.x*4;
  float wv = W[lane];
  for (int i = wid; i < n; i += nw){
    float v = x[i*64+lane]*wv;
    for (int o = 32; o > 0; o >>= 1) v += __shfl_xor(v, o);
    if (lane == 0) h1[i] = v;
  }
}

__global__ void k_zero_i(int* __restrict__ p, int n){
  int t = blockIdx.x*blockDim.x + threadIdx.x;
  if (t < n) p[t] = 0;
}

// ---- edge radix sort by dst: 3 stable passes of 6 bits (dst < 2^18) ----
__global__ void k_ehist6(const int* __restrict__ key, int* __restrict__ hist, int shift){
  __shared__ int lh[64];
  if (threadIdx.x < 64) lh[threadIdx.x] = 0;
  __syncthreads();
  int base = blockIdx.x*EB + threadIdx.x;
  #pragma unroll
  for (int u = 0; u < 8; u++)
    atomicAdd(&lh[(key[base + u*256] >> shift) & 63], 1);
  __syncthreads();
  if (threadIdx.x < 64) hist[threadIdx.x*ENB + blockIdx.x] = lh[threadIdx.x];
}

__global__ void k_escatter6(const int* __restrict__ keyin, const int* __restrict__ valin,
                            int* __restrict__ keyout, int* __restrict__ valout,
                            const int* __restrict__ hist, int shift){
  __shared__ int dbase[64], run[64], wcnt[4][64];
  int t = threadIdx.x, lane = t & 63, w = t >> 6;
  if (t < 64){ dbase[t] = hist[t*ENB + blockIdx.x]; run[t] = 0; }
  __syncthreads();
  for (int u = 0; u < 8; u++){
    if (t < 64){ wcnt[0][t]=0; wcnt[1][t]=0; wcnt[2][t]=0; wcnt[3][t]=0; }
    __syncthreads();
    int g = blockIdx.x*EB + u*256 + t;
    int kk = keyin[g], vv = valin[g];
    int d = (kk >> shift) & 63;
    unsigned long long m = ~0ull;
    #pragma unroll
    for (int b = 0; b < 6; b++){
      unsigned long long bal = __ballot((d >> b) & 1);
      m &= ((d >> b) & 1) ? bal : ~bal;
    }
    int rnk = __popcll(m & ((1ull << lane) - 1ull));
    if (rnk == 0) wcnt[w][d] = __popcll(m);
    __syncthreads();
    int off2 = run[d] + rnk;
    for (int w2 = 0; w2 < w; w2++) off2 += wcnt[w2][d];
    int pos = dbase[d] + off2;
    keyout[pos] = kk; valout[pos] = vv;
    __syncthreads();
    if (t < 64) run[t] += wcnt[0][t] + wcnt[1][t] + wcnt[2][t] + wcnt[3][t];
    __syncthreads();
  }
}

// rp + dinv from sorted dst keys via binary search (one thread per node)
__global__ void k_rp_search(const int* __restrict__ skey, int* __restrict__ rp,
                            float* __restrict__ dinvA, float* __restrict__ dinvB, int n){
  int i = blockIdx.x*blockDim.x + threadIdx.x;
  if (i >= n) return;
  int lo = 0, hi = NE;
  while (lo < hi){ int mid = (lo+hi)>>1; if (skey[mid] < i) lo = mid+1; else hi = mid; }
  int a = lo;
  lo = a; hi = NE;
  while (lo < hi){ int mid = (lo+hi)>>1; if (skey[mid] < i+1) lo = mid+1; else hi = mid; }
  int b2 = lo;
  rp[i] = a;
  if (i == n-1) rp[n] = NE;
  float deg = (float)(b2 - a);
  dinvA[i] = 1.0f/sqrtf(deg + 2.f);
  dinvB[i] = 1.0f/sqrtf(deg + 1.f);
}

// ---- parallel exclusive scan (2048 elems/block) ----
__global__ void k_scan_part(const int* __restrict__ in, int* __restrict__ bsum, int n){
  __shared__ int ws[256];
  int base = blockIdx.x*2048 + threadIdx.x*8;
  int s = 0;
  #pragma unroll
  for (int u = 0; u < 8; u++){ int i = base+u; if (i < n) s += in[i]; }
  ws[threadIdx.x] = s; __syncthreads();
  for (int st = 128; st > 0; st >>= 1){
    if (threadIdx.x < st) ws[threadIdx.x] += ws[threadIdx.x+st];
    __syncthreads();
  }
  if (threadIdx.x == 0) bsum[blockIdx.x] = ws[0];
}

// final scan stage for CSR: rp[0..n] + fused dinv (fill=2)
__global__ void k_scan_fin_rp(const int* __restrict__ in, const int* __restrict__ bsum, int nb,
                              int* __restrict__ rp, float* __restrict__ dinvA, int n){
  __shared__ int bws[256]; __shared__ int ws[256];
  int t = threadIdx.x;
  bws[t] = (t < nb) ? bsum[t] : 0; __syncthreads();
  for (int st = 1; st < 256; st <<= 1){
    int a = (t >= st) ? bws[t-st] : 0; __syncthreads();
    bws[t] += a; __syncthreads();
  }
  int blockoff = (blockIdx.x == 0) ? 0 : bws[blockIdx.x-1];
  int base = blockIdx.x*2048 + t*8;
  int v[8]; int s = 0;
  #pragma unroll
  for (int u = 0; u < 8; u++){ int i = base+u; v[u] = (i < n) ? in[i] : 0; s += v[u]; }
  ws[t] = s; __syncthreads();
  for (int st = 1; st < 256; st <<= 1){
    int a = (t >= st) ? ws[t-st] : 0; __syncthreads();
    ws[t] += a; __syncthreads();
  }
  int off = blockoff + ws[t] - s;
  #pragma unroll
  for (int u = 0; u < 8; u++){
    int i = base+u;
    if (i < n){
      rp[i] = off; off += v[u];
      dinvA[i] = 1.0f/sqrtf((float)v[u] + 2.f);
      if (i == n-1) rp[n] = off;
    }
  }
}

// final scan stage, in-place flat (edge-sort hist)
__global__ void k_scan_fin_flat(int* __restrict__ data, const int* __restrict__ bsum, int nb, int n){
  __shared__ int bws[256]; __shared__ int ws[256];
  int t = threadIdx.x;
  bws[t] = (t < nb) ? bsum[t] : 0; __syncthreads();
  for (int st = 1; st < 256; st <<= 1){
    int a = (t >= st) ? bws[t-st] : 0; __syncthreads();
    bws[t] += a; __syncthreads();
  }
  int blockoff = (blockIdx.x == 0) ? 0 : bws[blockIdx.x-1];
  int base = blockIdx.x*2048 + t*8;
  int v[8]; int s = 0;
  #pragma unroll
  for (int u = 0; u < 8; u++){ int i = base+u; v[u] = (i < n) ? data[i] : 0; s += v[u]; }
  ws[t] = s; __syncthreads();
  for (int st = 1; st < 256; st <<= 1){
    int a = (t >= st) ? ws[t-st] : 0; __syncthreads();
    ws[t] += a; __syncthreads();
  }
  int off = blockoff + ws[t] - s;
  #pragma unroll
  for (int u = 0; u < 8; u++){
    int i = base+u;
    if (i < n){ data[i] = off; off += v[u]; }
  }
}

// ---- CSR for pooled level from parent CSR + injective mapping ----
__global__ void k_hist_mapped(const int* __restrict__ rp_p, const int* __restrict__ col_p,
                              const int* __restrict__ mapv, int* __restrict__ indeg, int np){
  int d = blockIdx.x*blockDim.x + threadIdx.x;
  if (d >= np) return;
  int md = mapv[d];
  if (md < 0) return;
  int c = 0, e = rp_p[d+1];
  int j = rp_p[d];
  for (; j + 4 <= e; j += 4){
    int c0 = (mapv[col_p[j]]   >= 0);
    int c1 = (mapv[col_p[j+1]] >= 0);
    int c2 = (mapv[col_p[j+2]] >= 0);
    int c3 = (mapv[col_p[j+3]] >= 0);
    c += (c0+c1) + (c2+c3);
  }
  for (; j < e; j++) if (mapv[col_p[j]] >= 0) c++;
  indeg[md] = c;
}
__global__ void k_scatter_mapped(const int* __restrict__ rp_p, const int* __restrict__ col_p,
                                 const int* __restrict__ mapv, const int* __restrict__ rp_c,
                                 int* __restrict__ col_c, int np){
  int d = blockIdx.x*blockDim.x + threadIdx.x;
  if (d >= np) return;
  int md = mapv[d];
  if (md < 0) return;
  int pos = rp_c[md], e = rp_p[d+1];
  int j = rp_p[d];
  for (; j + 4 <= e; j += 4){
    int m0 = mapv[col_p[j]], m1 = mapv[col_p[j+1]];
    int m2 = mapv[col_p[j+2]], m3 = mapv[col_p[j+3]];
    if (m0 >= 0) col_c[pos++] = m0;
    if (m1 >= 0) col_c[pos++] = m1;
    if (m2 >= 0) col_c[pos++] = m2;
    if (m3 >= 0) col_c[pos++] = m3;
  }
  for (; j < e; j++){
    int ms = mapv[col_p[j]];
    if (ms >= 0) col_c[pos++] = ms;
  }
}

// 3-wide gather for the first conv (x_in has C_IN=3), 4-way unrolled
__global__ void k_gather3(const int* __restrict__ rp, const int* __restrict__ col,
                          const float* __restrict__ dinv, const float* __restrict__ x,
                          float* __restrict__ y, int n){
  int i = blockIdx.x*blockDim.x + threadIdx.x;
  if (i >= n) return;
  int beg = rp[i], end = rp[i+1];
  float di = dinv[i];
  float a0 = 0.f, a1 = 0.f, a2 = 0.f;
  int j = beg;
  for (; j + 4 <= end; j += 4){
    int s0 = col[j], s1 = col[j+1], s2 = col[j+2], s3 = col[j+3];
    float d0 = dinv[s0], d1 = dinv[s1], d2 = dinv[s2], d3 = dinv[s3];
    a0 += d0*x[s0*3+0] + d1*x[s1*3+0] + d2*x[s2*3+0] + d3*x[s3*3+0];
    a1 += d0*x[s0*3+1] + d1*x[s1*3+1] + d2*x[s2*3+1] + d3*x[s3*3+1];
    a2 += d0*x[s0*3+2] + d1*x[s1*3+2] + d2*x[s2*3+2] + d3*x[s3*3+2];
  }
  for (; j < end; j++){
    int s = col[j];
    float ds = dinv[s];
    a0 += ds*x[s*3+0]; a1 += ds*x[s*3+1]; a2 += ds*x[s*3+2];
  }
  float sl = 2.f*di*di;
  y[i*3+0] = di*a0 + sl*x[i*3+0];
  y[i*3+1] = di*a1 + sl*x[i*3+1];
  y[i*3+2] = di*a2 + sl*x[i*3+2];
}

// final conv (Fout=1, fill=1) fused with sigmoid; 4-way unrolled
__global__ void k_gather_sig(const int* __restrict__ rp, const int* __restrict__ col,
                             const float* __restrict__ dinv, const float* __restrict__ h1,
                             float* __restrict__ out, int n){
  int i = blockIdx.x*blockDim.x + threadIdx.x;
  if (i >= n) return;
  int beg = rp[i], end = rp[i+1];
  float di = dinv[i];
  float acc = 0.f;
  int j = beg;
  for (; j + 4 <= end; j += 4){
    int s0 = col[j], s1 = col[j+1], s2 = col[j+2], s3 = col[j+3];
    float v0 = dinv[s0]*h1[s0];
    float v1 = dinv[s1]*h1[s1];
    float v2 = dinv[s2]*h1[s2];
    float v3 = dinv[s3]*h1[s3];
    acc += (v0+v1) + (v2+v3);
  }
  for (; j < end; j++) acc += dinv[col[j]]*h1[col[j]];
  float v = di*acc + di*di*h1[i];
  out[i] = 1.f/(1.f+expf(-v));
}

// FUSED BN+ReLU + scatter-add into residual (up-path skip connections)
__global__ void k_bnrelu_scatter(const float* __restrict__ x, const float* __restrict__ stats,
                                 const float* __restrict__ gamma, const float* __restrict__ beta,
                                 const int* __restrict__ perm, float* __restrict__ res, int n){
  int t = blockIdx.x*blockDim.x + threadIdx.x;
  if (t >= n*64) return;
  int r = t >> 6, f = t & 63;
  float inv_n = 1.0f/(float)n;
  float mu = stats[f]*inv_n;
  float var = stats[64+f]*inv_n - mu*mu;
  float v = gamma[f]*(x[t]-mu)*(1.0f/sqrtf(var+1e-5f)) + beta[f];
  res[perm[r]*64+f] += fmaxf(v, 0.f);
}

// fused BN+ReLU (in-place) + pool score + radix init + pass-0 histogram
__global__ void k_bnrelu_score(float* __restrict__ x, const float* __restrict__ stats,
                               const float* __restrict__ gamma, const float* __restrict__ beta,
                               const float* __restrict__ pw,
                               float* __restrict__ score, unsigned* __restrict__ key,
                               int* __restrict__ idx, int* __restrict__ hist0,
                               int nblk, int n, int P){
  int lane = threadIdx.x & 63, w = threadIdx.x >> 6;
  int wid = blockIdx.x*4 + w, nw = gridDim.x*4;
  float inv_n = 1.f/(float)n;
  float mu = stats[lane]*inv_n;
  float var = stats[64+lane]*inv_n - mu*mu;
  float gs = gamma[lane]*(1.f/sqrtf(var+1e-5f));
  float bt = beta[lane];
  float pv = pw[lane];
  float q = pv*pv;
  for (int o = 32; o > 0; o >>= 1) q += __shfl_xor(q, o);
  float qn = 1.f/sqrtf(q);
  for (int i = wid; i < n; i += nw){
    float v = fmaxf(gs*(x[i*64+lane]-mu)+bt, 0.f);
    x[i*64+lane] = v;
    float s = v*pv;
    for (int o = 32; o > 0; o >>= 1) s += __shfl_xor(s, o);
    if (lane == 0){
      float sc = fmaxf(s*qn, 0.f);
      unsigned kv = ~__float_as_uint(sc);
      score[i] = sc; key[i] = kv; idx[i] = i;
      atomicAdd(&hist0[(kv & 255u)*nblk + (i >> 10)], 1);
    }
  }
  for (int g = n + wid; g < P; g += nw)
    if (lane == 0){
      key[g] = 0xFFFFFFFFu; idx[g] = 0;
      atomicAdd(&hist0[255*nblk + (g >> 10)], 1);
    }
}

// ---- score radix scatter; also builds the NEXT pass's histogram ----
__global__ void k_radix_scatter(const unsigned* __restrict__ keyin, const int* __restrict__ idxin,
                                unsigned* __restrict__ keyout, int* __restrict__ idxout,
                                const int* __restrict__ hist, int* __restrict__ hnext,
                                int shift, int nblk){
  __shared__ int dbase[256], run[256], sc[256];
  __shared__ int wcnt[4][256];
  int t = threadIdx.x, lane = t & 63, w = t >> 6;
  int pre = 0, tot = 0;
  for (int b = 0; b < nblk; b++){
    int v = hist[t*nblk + b];
    if (b < blockIdx.x) pre += v;
    tot += v;
  }
  sc[t] = tot; __syncthreads();
  for (int st = 1; st < 256; st <<= 1){
    int a = (t >= st) ? sc[t-st] : 0; __syncthreads();
    sc[t] += a; __syncthreads();
  }
  dbase[t] = sc[t] - tot + pre;
  run[t] = 0;
  for (int u = 0; u < 4; u++){
    wcnt[0][t] = 0; wcnt[1][t] = 0; wcnt[2][t] = 0; wcnt[3][t] = 0;
    __syncthreads();
    int g = blockIdx.x*1024 + u*256 + t;
    unsigned kk = keyin[g]; int id = idxin[g];
    unsigned d = (kk >> shift) & 255u;
    unsigned long long m = ~0ull;
    #pragma unroll
    for (int b = 0; b < 8; b++){
      unsigned long long bal = __ballot((d >> b) & 1u);
      m &= ((d >> b) & 1u) ? bal : ~bal;
    }
    int rnk = __popcll(m & ((1ull << lane) - 1ull));
    if (rnk == 0) wcnt[w][d] = __popcll(m);
    __syncthreads();
    int off2 = run[d] + rnk;
    for (int w2 = 0; w2 < w; w2++) off2 += wcnt[w2][d];
    int pos = dbase[d] + off2;
    keyout[pos] = kk; idxout[pos] = id;
    if (hnext){
      unsigned d2 = (kk >> (shift+8)) & 255u;
      atomicAdd(&hnext[d2*nblk + (pos >> 10)], 1);
    }
    __syncthreads();
    run[t] += wcnt[0][t] + wcnt[1][t] + wcnt[2][t] + wcnt[3][t];
    __syncthreads();
  }
}

// merged select + gather-scale
__global__ void k_select_gather(const int* __restrict__ idxs, const float* __restrict__ x,
                                const float* __restrict__ score, int* __restrict__ perm,
                                int* __restrict__ mapv, float* __restrict__ xk, int n, int k){
  int t = blockIdx.x*blockDim.x + threadIdx.x;
  if (t < n){
    int i = idxs[t];
    mapv[i] = (t < k) ? t : -1;
    if (t < k) perm[t] = i;
  }
  if (t < k*64){
    int r = t >> 6, f = t & 63;
    int i = idxs[r];
    xk[t] = x[i*64+f]*score[i];
  }
}

extern "C" void kernel_launch(void* const* d_in, const int* in_sizes, int n_in,
                              void* d_out, int out_size, void* d_ws, size_t ws_size,
                              hipStream_t stream) {
  const float* x_in = (const float*)d_in[0];
  const int* ei = (const int*)d_in[1];
  const int* src0 = ei;
  const int* dst0 = ei + NE;
  const float* W_d[4] = {(const float*)d_in[2],(const float*)d_in[5],(const float*)d_in[8],(const float*)d_in[11]};
  const float* g_d[4] = {(const float*)d_in[3],(const float*)d_in[6],(const float*)d_in[9],(const float*)d_in[12]};
  const float* b_d[4] = {(const float*)d_in[4],(const float*)d_in[7],(const float*)d_in[10],(const float*)d_in[13]};
  const float* pw[3]  = {(const float*)d_in[14],(const float*)d_in[15],(const float*)d_in[16]};
  const float* W_u[2] = {(const float*)d_in[17],(const float*)d_in[20]};
  const float* g_u[2] = {(const float*)d_in[18],(const float*)d_in[21]};
  const float* b_u[2] = {(const float*)d_in[19],(const float*)d_in[22]};
  const float* W_out  = (const float*)d_in[23];
  float* out = (float*)d_out;

  float* base = (float*)d_ws;
  size_t off = 0;
  auto alloc = [&](size_t nf){ float* p = base + off; off += nf; return p; };
  float* x0 = alloc(5120000);
  float* x1 = alloc(2560000);
  float* x2 = alloc(1280000);
  float* x3 = alloc(640000);
  float* A  = alloc(2560000);
  float* h3 = alloc(240000);           // gathered 3-wide rows for first conv
  int* col0 = (int*)alloc(NE);
  int* col1 = (int*)alloc(NE);
  int* col2 = (int*)alloc(NE);
  int* col3 = (int*)alloc(NE);
  int* ek1 = (int*)alloc(NE);
  int* ev1 = (int*)alloc(NE);
  int* ek2 = (int*)alloc(NE);
  int* ev2 = (int*)alloc(NE);
  int* rp0 = (int*)alloc(80001);
  int* rp1 = (int*)alloc(40001);
  int* rp2 = (int*)alloc(20001);
  int* rp3 = (int*)alloc(10001);
  int* indeg  = (int*)alloc(NN0);
  float* dinv0  = alloc(NN0);
  float* dinv0f = alloc(NN0);
  float* dinv1  = alloc(40000);
  float* dinv2  = alloc(20000);
  float* dinv3  = alloc(10000);
  float* score = alloc(NN0);
  int* mapv = (int*)alloc(NN0);
  int* p0 = (int*)alloc(40000);
  int* p1 = (int*)alloc(20000);
  int* p2 = (int*)alloc(10000);
  float* stats = alloc(128);
  float* part  = alloc(MMB_GRID*128);
  unsigned* keyA = (unsigned*)alloc(81920);
  unsigned* keyB = (unsigned*)alloc(81920);
  int* idxA = (int*)alloc(81920);
  int* idxB = (int*)alloc(81920);
  int* hists = (int*)alloc(4*HSTRIDE);   // 4 per-pass score histograms
  int* ehist = (int*)alloc(64*ENB);
  int* bsum = (int*)alloc(256);
  (void)ws_size; (void)in_sizes; (void)n_in; (void)out_size;

  const int B = 256;

  auto scan_flat = [&](int* data, int n2){
    int nb = cdiv(n2, 2048);
    k_scan_part    <<<nb, 256, 0, stream>>>(data, bsum, n2);
    k_scan_fin_flat<<<nb, 256, 0, stream>>>(data, bsum, nb, n2);
  };
  auto scan_csr = [&](const int* indeg_, int* rp, float* dv, int n2){
    int nb = cdiv(n2, 2048);
    k_scan_part  <<<nb, 256, 0, stream>>>(indeg_, bsum, n2);
    k_scan_fin_rp<<<nb, 256, 0, stream>>>(indeg_, bsum, nb, rp, dv, n2);
  };

  auto conv = [&](const float* xin, const float* W, int n,
                  const int* rp, const int* col, const float* dv, float* dstb){
    k_conv64<<<MMB_GRID, B, 0, stream>>>(rp, col, dv, xin, W, dstb, part, n);
    k_stats_reduce<<<128, 64, 0, stream>>>(part, stats);
  };

  auto pool = [&](float* xb, const float* g, const float* bt, const float* w,
                  int n, int k, int* pm, float* xk){
    int nblk = cdiv(n, 1024), P = nblk*1024;
    k_zero_i<<<cdiv(4*HSTRIDE,B), B, 0, stream>>>(hists, 4*HSTRIDE);
    k_bnrelu_score<<<1024, B, 0, stream>>>(xb, stats, g, bt, w, score, keyA, idxA,
                                           hists, nblk, n, P);
    unsigned* ka = keyA; int* ia = idxA; unsigned* kb = keyB; int* ib = idxB;
    for (int pass = 0; pass < 4; pass++){
      int* hin = hists + pass*HSTRIDE;
      int* hnx = (pass < 3) ? hists + (pass+1)*HSTRIDE : nullptr;
      k_radix_scatter<<<nblk, 256, 0, stream>>>(ka, ia, kb, ib, hin, hnx, pass*8, nblk);
      std::swap(ka, kb); std::swap(ia, ib);
    }
    k_select_gather<<<cdiv(k*64,B), B, 0, stream>>>(ia, xb, score, pm, mapv, xk, n, k);
  };

  auto csr_mapped = [&](const int* rp_p, const int* col_p, int np, int nc,
                        int* rp_c, int* col_c, float* dv){
    k_hist_mapped<<<cdiv(np,B), B, 0, stream>>>(rp_p, col_p, mapv, indeg, np);
    scan_csr(indeg, rp_c, dv, nc);
    k_scatter_mapped<<<cdiv(np,B), B, 0, stream>>>(rp_p, col_p, mapv, rp_c, col_c, np);
  };

  // ---- level-0 CSR: 3-pass 6-bit LSD radix sort of edges by dst ----
  k_ehist6   <<<ENB, B, 0, stream>>>(dst0, ehist, 0);
  scan_flat(ehist, 64*ENB);
  k_escatter6<<<ENB, B, 0, stream>>>(dst0, src0, ek1, ev1, ehist, 0);
  k_ehist6   <<<ENB, B, 0, stream>>>(ek1, ehist, 6);
  scan_flat(ehist, 64*ENB);
  k_escatter6<<<ENB, B, 0, stream>>>(ek1, ev1, ek2, ev2, ehist, 6);
  k_ehist6   <<<ENB, B, 0, stream>>>(ek2, ehist, 12);
  scan_flat(ehist, 64*ENB);
  k_escatter6<<<ENB, B, 0, stream>>>(ek2, ev2, ek1, col0, ehist, 12);
  k_rp_search<<<cdiv(NN0,B), B, 0, stream>>>(ek1, rp0, dinv0, dinv0f, NN0);

  // ---- down path ----
  k_gather3   <<<cdiv(NN0,B), B, 0, stream>>>(rp0, col0, dinv0, x_in, h3, NN0);
  k_matmul_bn3<<<MMB_GRID, B, 0, stream>>>(h3, W_d[0], x0, part, NN0);
  k_stats_reduce<<<128, 64, 0, stream>>>(part, stats);
  pool(x0, g_d[0], b_d[0], pw[0], NN0, 40000, p0, A);
  csr_mapped(rp0, col0, NN0, 40000, rp1, col1, dinv1);

  conv(A, W_d[1], 40000, rp1, col1, dinv1, x1);
  pool(x1, g_d[1], b_d[1], pw[1], 40000, 20000, p1, A);
  csr_mapped(rp1, col1, 40000, 20000, rp2, col2, dinv2);

  conv(A, W_d[2], 20000, rp2, col2, dinv2, x2);
  pool(x2, g_d[2], b_d[2], pw[2], 20000, 10000, p2, A);
  csr_mapped(rp2, col2, 20000, 10000, rp3, col3, dinv3);

  conv(A, W_d[3], 10000, rp3, col3, dinv3, x3);

  // ---- up path (BN+ReLU fused into the skip-connection scatter-add) ----
  k_bnrelu_scatter<<<cdiv(10000*64,B), B, 0, stream>>>(x3, stats, g_d[3], b_d[3], p2, x2, 10000);
  conv(x2, W_u[0], 20000, rp2, col2, dinv2, A);
  k_bnrelu_scatter<<<cdiv(20000*64,B), B, 0, stream>>>(A, stats, g_u[0], b_u[0], p1, x1, 20000);
  conv(x1, W_u[1], 40000, rp1, col1, dinv1, A);
  k_bnrelu_scatter<<<cdiv(40000*64,B), B, 0, stream>>>(A, stats, g_u[1], b_u[1], p0, x0, 40000);

  // ---- final conv (fill = 1.0) fused with sigmoid ----
  float* h1 = score;  // reuse
  k_matvec<<<512, B, 0, stream>>>(x0, W_out, h1, NN0);
  k_gather_sig<<<cdiv(NN0,B), B, 0, stream>>>(rp0, col0, dinv0f, h1, out, NN0);
}

// Round 15
// 742.867 us; speedup vs baseline: 3.4687x; 3.4687x over previous
//
#include <hip/hip_runtime.h>
#include <cstdint>
#include <utility>

#define NN0 80000
#define NE 1280000
#define MMB_GRID 2048
#define EB 2048          // elems per block in edge sort (NE/EB = 625 exact)
#define ENB 625

static inline int cdiv(int a, int b){ return (a+b-1)/b; }

// ---- FUSED conv: gather (x-space) + matmul [64,64] + BN partials ----
__global__ void k_conv64(const int* __restrict__ rp, const int* __restrict__ col,
                         const float* __restrict__ dinv, const float* __restrict__ x,
                         const float* __restrict__ W, float* __restrict__ out,
                         float* __restrict__ part, int n){
  __shared__ float yl[4][64];
  __shared__ float ls[64], lq[64];
  int lane = threadIdx.x & 63, w = threadIdx.x >> 6;
  if (threadIdx.x < 64){ ls[threadIdx.x] = 0.f; lq[threadIdx.x] = 0.f; }
  __syncthreads();
  float sa = 0.f, sq = 0.f;
  int wid = blockIdx.x*4 + w, nw = gridDim.x*4;
  for (int i = wid; i < n; i += nw){
    int beg = rp[i], end = rp[i+1];
    float di = dinv[i];
    float y = 0.f;
    int j = beg;
    for (; j + 4 <= end; j += 4){
      int s0 = col[j], s1 = col[j+1], s2 = col[j+2], s3 = col[j+3];
      float y0 = dinv[s0]*x[s0*64+lane];
      float y1 = dinv[s1]*x[s1*64+lane];
      float y2 = dinv[s2]*x[s2*64+lane];
      float y3 = dinv[s3]*x[s3*64+lane];
      y += (y0+y1) + (y2+y3);
    }
    for (; j < end; j++){ int s = col[j]; y += dinv[s]*x[s*64+lane]; }
    y = di*y + 2.f*di*di*x[i*64+lane];
    yl[w][lane] = y;
    float acc = 0.f;
    #pragma unroll
    for (int k2 = 0; k2 < 64; k2++)
      acc += yl[w][k2]*W[k2*64+lane];
    out[i*64+lane] = acc;
    sa += acc; sq += acc*acc;
  }
  atomicAdd(&ls[lane], sa); atomicAdd(&lq[lane], sq);
  __syncthreads();
  if (threadIdx.x < 128)
    part[blockIdx.x*128 + threadIdx.x] =
      (threadIdx.x < 64) ? ls[threadIdx.x] : lq[threadIdx.x-64];
}

// Fin=3 matmul (first conv), reads gathered y3 rows
__global__ void k_matmul_bn3(const float* __restrict__ x, const float* __restrict__ W,
                             float* __restrict__ h, float* __restrict__ part, int n){
  __shared__ float ls[64], lq[64];
  int f = threadIdx.x & 63;
  float sa = 0.f, sq = 0.f;
  int total = n*64, stride = gridDim.x*blockDim.x;
  for (int t = blockIdx.x*blockDim.x + threadIdx.x; t < total; t += stride){
    int i = t >> 6;
    float s = x[i*3]*W[f] + x[i*3+1]*W[64+f] + x[i*3+2]*W[128+f];
    h[t] = s; sa += s; sq += s*s;
  }
  if (threadIdx.x < 64){ ls[threadIdx.x] = 0.f; lq[threadIdx.x] = 0.f; }
  __syncthreads();
  atomicAdd(&ls[f], sa); atomicAdd(&lq[f], sq);
  __syncthreads();
  if (threadIdx.x < 128)
    part[blockIdx.x*128 + threadIdx.x] =
      (threadIdx.x < 64) ? ls[threadIdx.x] : lq[threadIdx.x-64];
}

__global__ void k_stats_reduce(const float* __restrict__ part, float* __restrict__ stats){
  int c = blockIdx.x, lane = threadIdx.x;
  float s = 0.f;
  for (int b = lane; b < MMB_GRID; b += 64) s += part[b*128 + c];
  for (int o = 32; o > 0; o >>= 1) s += __shfl_xor(s, o);
  if (lane == 0) stats[c] = s;
}

__global__ void k_matvec(const float* __restrict__ x, const float* __restrict__ W,
                         float* __restrict__ h1, int n){
  int lane = threadIdx.x & 63, w = threadIdx.x >> 6;
  int wid = blockIdx.x*4 + w, nw = gridDim.x*4;
  float wv = W[lane];
  for (int i = wid; i < n; i += nw){
    float v = x[i*64+lane]*wv;
    for (int o = 32; o > 0; o >>= 1) v += __shfl_xor(v, o);
    if (lane == 0) h1[i] = v;
  }
}

// ---- edge radix sort by dst: 3 stable passes of 6 bits (dst < 2^18) ----
__global__ void k_ehist6(const int* __restrict__ key, int* __restrict__ hist, int shift){
  __shared__ int lh[64];
  if (threadIdx.x < 64) lh[threadIdx.x] = 0;
  __syncthreads();
  int base = blockIdx.x*EB + threadIdx.x;
  #pragma unroll
  for (int u = 0; u < 8; u++)
    atomicAdd(&lh[(key[base + u*256] >> shift) & 63], 1);
  __syncthreads();
  if (threadIdx.x < 64) hist[threadIdx.x*ENB + blockIdx.x] = lh[threadIdx.x];
}

__global__ void k_escatter6(const int* __restrict__ keyin, const int* __restrict__ valin,
                            int* __restrict__ keyout, int* __restrict__ valout,
                            const int* __restrict__ hist, int shift){
  __shared__ int dbase[64], run[64], wcnt[4][64];
  int t = threadIdx.x, lane = t & 63, w = t >> 6;
  if (t < 64){ dbase[t] = hist[t*ENB + blockIdx.x]; run[t] = 0; }
  __syncthreads();
  for (int u = 0; u < 8; u++){
    if (t < 64){ wcnt[0][t]=0; wcnt[1][t]=0; wcnt[2][t]=0; wcnt[3][t]=0; }
    __syncthreads();
    int g = blockIdx.x*EB + u*256 + t;
    int kk = keyin[g], vv = valin[g];
    int d = (kk >> shift) & 63;
    unsigned long long m = ~0ull;
    #pragma unroll
    for (int b = 0; b < 6; b++){
      unsigned long long bal = __ballot((d >> b) & 1);
      m &= ((d >> b) & 1) ? bal : ~bal;
    }
    int rnk = __popcll(m & ((1ull << lane) - 1ull));
    if (rnk == 0) wcnt[w][d] = __popcll(m);
    __syncthreads();
    int off2 = run[d] + rnk;
    for (int w2 = 0; w2 < w; w2++) off2 += wcnt[w2][d];
    int pos = dbase[d] + off2;
    keyout[pos] = kk; valout[pos] = vv;
    __syncthreads();
    if (t < 64) run[t] += wcnt[0][t] + wcnt[1][t] + wcnt[2][t] + wcnt[3][t];
    __syncthreads();
  }
}

// rp + dinv from sorted dst keys via binary search (one thread per node)
__global__ void k_rp_search(const int* __restrict__ skey, int* __restrict__ rp,
                            float* __restrict__ dinvA, float* __restrict__ dinvB, int n){
  int i = blockIdx.x*blockDim.x + threadIdx.x;
  if (i >= n) return;
  int lo = 0, hi = NE;
  while (lo < hi){ int mid = (lo+hi)>>1; if (skey[mid] < i) lo = mid+1; else hi = mid; }
  int a = lo;
  lo = a; hi = NE;
  while (lo < hi){ int mid = (lo+hi)>>1; if (skey[mid] < i+1) lo = mid+1; else hi = mid; }
  int b2 = lo;
  rp[i] = a;
  if (i == n-1) rp[n] = NE;
  float deg = (float)(b2 - a);
  dinvA[i] = 1.0f/sqrtf(deg + 2.f);
  dinvB[i] = 1.0f/sqrtf(deg + 1.f);
}

// ---- parallel exclusive scan (2048 elems/block) ----
__global__ void k_scan_part(const int* __restrict__ in, int* __restrict__ bsum, int n){
  __shared__ int ws[256];
  int base = blockIdx.x*2048 + threadIdx.x*8;
  int s = 0;
  #pragma unroll
  for (int u = 0; u < 8; u++){ int i = base+u; if (i < n) s += in[i]; }
  ws[threadIdx.x] = s; __syncthreads();
  for (int st = 128; st > 0; st >>= 1){
    if (threadIdx.x < st) ws[threadIdx.x] += ws[threadIdx.x+st];
    __syncthreads();
  }
  if (threadIdx.x == 0) bsum[blockIdx.x] = ws[0];
}

// final scan stage for CSR: rp[0..n] + fused dinv (fill=2)
__global__ void k_scan_fin_rp(const int* __restrict__ in, const int* __restrict__ bsum, int nb,
                              int* __restrict__ rp, float* __restrict__ dinvA, int n){
  __shared__ int bws[256]; __shared__ int ws[256];
  int t = threadIdx.x;
  bws[t] = (t < nb) ? bsum[t] : 0; __syncthreads();
  for (int st = 1; st < 256; st <<= 1){
    int a = (t >= st) ? bws[t-st] : 0; __syncthreads();
    bws[t] += a; __syncthreads();
  }
  int blockoff = (blockIdx.x == 0) ? 0 : bws[blockIdx.x-1];
  int base = blockIdx.x*2048 + t*8;
  int v[8]; int s = 0;
  #pragma unroll
  for (int u = 0; u < 8; u++){ int i = base+u; v[u] = (i < n) ? in[i] : 0; s += v[u]; }
  ws[t] = s; __syncthreads();
  for (int st = 1; st < 256; st <<= 1){
    int a = (t >= st) ? ws[t-st] : 0; __syncthreads();
    ws[t] += a; __syncthreads();
  }
  int off = blockoff + ws[t] - s;
  #pragma unroll
  for (int u = 0; u < 8; u++){
    int i = base+u;
    if (i < n){
      rp[i] = off; off += v[u];
      dinvA[i] = 1.0f/sqrtf((float)v[u] + 2.f);
      if (i == n-1) rp[n] = off;
    }
  }
}

// final scan stage, in-place flat (edge-sort hist)
__global__ void k_scan_fin_flat(int* __restrict__ data, const int* __restrict__ bsum, int nb, int n){
  __shared__ int bws[256]; __shared__ int ws[256];
  int t = threadIdx.x;
  bws[t] = (t < nb) ? bsum[t] : 0; __syncthreads();
  for (int st = 1; st < 256; st <<= 1){
    int a = (t >= st) ? bws[t-st] : 0; __syncthreads();
    bws[t] += a; __syncthreads();
  }
  int blockoff = (blockIdx.x == 0) ? 0 : bws[blockIdx.x-1];
  int base = blockIdx.x*2048 + t*8;
  int v[8]; int s = 0;
  #pragma unroll
  for (int u = 0; u < 8; u++){ int i = base+u; v[u] = (i < n) ? data[i] : 0; s += v[u]; }
  ws[t] = s; __syncthreads();
  for (int st = 1; st < 256; st <<= 1){
    int a = (t >= st) ? ws[t-st] : 0; __syncthreads();
    ws[t] += a; __syncthreads();
  }
  int off = blockoff + ws[t] - s;
  #pragma unroll
  for (int u = 0; u < 8; u++){
    int i = base+u;
    if (i < n){ data[i] = off; off += v[u]; }
  }
}

// ---- CSR for pooled level from parent CSR + injective mapping ----
__global__ void k_hist_mapped(const int* __restrict__ rp_p, const int* __restrict__ col_p,
                              const int* __restrict__ mapv, int* __restrict__ indeg, int np){
  int d = blockIdx.x*blockDim.x + threadIdx.x;
  if (d >= np) return;
  int md = mapv[d];
  if (md < 0) return;
  int c = 0, e = rp_p[d+1];
  int j = rp_p[d];
  for (; j + 4 <= e; j += 4){
    int c0 = (mapv[col_p[j]]   >= 0);
    int c1 = (mapv[col_p[j+1]] >= 0);
    int c2 = (mapv[col_p[j+2]] >= 0);
    int c3 = (mapv[col_p[j+3]] >= 0);
    c += (c0+c1) + (c2+c3);
  }
  for (; j < e; j++) if (mapv[col_p[j]] >= 0) c++;
  indeg[md] = c;
}
__global__ void k_scatter_mapped(const int* __restrict__ rp_p, const int* __restrict__ col_p,
                                 const int* __restrict__ mapv, const int* __restrict__ rp_c,
                                 int* __restrict__ col_c, int np){
  int d = blockIdx.x*blockDim.x + threadIdx.x;
  if (d >= np) return;
  int md = mapv[d];
  if (md < 0) return;
  int pos = rp_c[md], e = rp_p[d+1];
  int j = rp_p[d];
  for (; j + 4 <= e; j += 4){
    int m0 = mapv[col_p[j]], m1 = mapv[col_p[j+1]];
    int m2 = mapv[col_p[j+2]], m3 = mapv[col_p[j+3]];
    if (m0 >= 0) col_c[pos++] = m0;
    if (m1 >= 0) col_c[pos++] = m1;
    if (m2 >= 0) col_c[pos++] = m2;
    if (m3 >= 0) col_c[pos++] = m3;
  }
  for (; j < e; j++){
    int ms = mapv[col_p[j]];
    if (ms >= 0) col_c[pos++] = ms;
  }
}

// 3-wide gather for the first conv (x_in has C_IN=3), 4-way unrolled
__global__ void k_gather3(const int* __restrict__ rp, const int* __restrict__ col,
                          const float* __restrict__ dinv, const float* __restrict__ x,
                          float* __restrict__ y, int n){
  int i = blockIdx.x*blockDim.x + threadIdx.x;
  if (i >= n) return;
  int beg = rp[i], end = rp[i+1];
  float di = dinv[i];
  float a0 = 0.f, a1 = 0.f, a2 = 0.f;
  int j = beg;
  for (; j + 4 <= end; j += 4){
    int s0 = col[j], s1 = col[j+1], s2 = col[j+2], s3 = col[j+3];
    float d0 = dinv[s0], d1 = dinv[s1], d2 = dinv[s2], d3 = dinv[s3];
    a0 += d0*x[s0*3+0] + d1*x[s1*3+0] + d2*x[s2*3+0] + d3*x[s3*3+0];
    a1 += d0*x[s0*3+1] + d1*x[s1*3+1] + d2*x[s2*3+1] + d3*x[s3*3+1];
    a2 += d0*x[s0*3+2] + d1*x[s1*3+2] + d2*x[s2*3+2] + d3*x[s3*3+2];
  }
  for (; j < end; j++){
    int s = col[j];
    float ds = dinv[s];
    a0 += ds*x[s*3+0]; a1 += ds*x[s*3+1]; a2 += ds*x[s*3+2];
  }
  float sl = 2.f*di*di;
  y[i*3+0] = di*a0 + sl*x[i*3+0];
  y[i*3+1] = di*a1 + sl*x[i*3+1];
  y[i*3+2] = di*a2 + sl*x[i*3+2];
}

// final conv (Fout=1, fill=1) fused with sigmoid; 4-way unrolled
__global__ void k_gather_sig(const int* __restrict__ rp, const int* __restrict__ col,
                             const float* __restrict__ dinv, const float* __restrict__ h1,
                             float* __restrict__ out, int n){
  int i = blockIdx.x*blockDim.x + threadIdx.x;
  if (i >= n) return;
  int beg = rp[i], end = rp[i+1];
  float di = dinv[i];
  float acc = 0.f;
  int j = beg;
  for (; j + 4 <= end; j += 4){
    int s0 = col[j], s1 = col[j+1], s2 = col[j+2], s3 = col[j+3];
    float v0 = dinv[s0]*h1[s0];
    float v1 = dinv[s1]*h1[s1];
    float v2 = dinv[s2]*h1[s2];
    float v3 = dinv[s3]*h1[s3];
    acc += (v0+v1) + (v2+v3);
  }
  for (; j < end; j++) acc += dinv[col[j]]*h1[col[j]];
  float v = di*acc + di*di*h1[i];
  out[i] = 1.f/(1.f+expf(-v));
}

// FUSED BN+ReLU + scatter-add into residual (up-path skip connections)
__global__ void k_bnrelu_scatter(const float* __restrict__ x, const float* __restrict__ stats,
                                 const float* __restrict__ gamma, const float* __restrict__ beta,
                                 const int* __restrict__ perm, float* __restrict__ res, int n){
  int t = blockIdx.x*blockDim.x + threadIdx.x;
  if (t >= n*64) return;
  int r = t >> 6, f = t & 63;
  float inv_n = 1.0f/(float)n;
  float mu = stats[f]*inv_n;
  float var = stats[64+f]*inv_n - mu*mu;
  float v = gamma[f]*(x[t]-mu)*(1.0f/sqrtf(var+1e-5f)) + beta[f];
  res[perm[r]*64+f] += fmaxf(v, 0.f);
}

// fused BN+ReLU (in-place) + pool score + radix init; wave-per-row
__global__ void k_bnrelu_score(float* __restrict__ x, const float* __restrict__ stats,
                               const float* __restrict__ gamma, const float* __restrict__ beta,
                               const float* __restrict__ pw,
                               float* __restrict__ score, unsigned* __restrict__ key,
                               int* __restrict__ idx, int n, int P){
  int lane = threadIdx.x & 63, w = threadIdx.x >> 6;
  int wid = blockIdx.x*4 + w, nw = gridDim.x*4;
  float inv_n = 1.f/(float)n;
  float mu = stats[lane]*inv_n;
  float var = stats[64+lane]*inv_n - mu*mu;
  float gs = gamma[lane]*(1.f/sqrtf(var+1e-5f));
  float bt = beta[lane];
  float pv = pw[lane];
  float q = pv*pv;
  for (int o = 32; o > 0; o >>= 1) q += __shfl_xor(q, o);
  float qn = 1.f/sqrtf(q);
  for (int i = wid; i < n; i += nw){
    float v = fmaxf(gs*(x[i*64+lane]-mu)+bt, 0.f);
    x[i*64+lane] = v;
    float s = v*pv;
    for (int o = 32; o > 0; o >>= 1) s += __shfl_xor(s, o);
    if (lane == 0){
      float sc = fmaxf(s*qn, 0.f);
      score[i] = sc; key[i] = ~__float_as_uint(sc); idx[i] = i;
    }
  }
  for (int g = n + wid; g < P; g += nw)
    if (lane == 0){ key[g] = 0xFFFFFFFFu; idx[g] = 0; }
}

// ---- score radix sort: 2 kernels/pass, 1024 elems/block ----
__global__ void k_radix_hist(const unsigned* __restrict__ key, int* __restrict__ hist,
                             int shift, int nblk){
  __shared__ int lh[256];
  lh[threadIdx.x] = 0; __syncthreads();
  int base = blockIdx.x*1024 + threadIdx.x;
  #pragma unroll
  for (int u = 0; u < 4; u++){
    unsigned d = (key[base + u*256] >> shift) & 255u;
    atomicAdd(&lh[d], 1);
  }
  __syncthreads();
  hist[threadIdx.x*nblk + blockIdx.x] = lh[threadIdx.x];
}

__global__ void k_radix_scatter(const unsigned* __restrict__ keyin, const int* __restrict__ idxin,
                                unsigned* __restrict__ keyout, int* __restrict__ idxout,
                                const int* __restrict__ hist, int shift, int nblk){
  __shared__ int dbase[256], run[256], sc[256];
  __shared__ int wcnt[4][256];
  int t = threadIdx.x, lane = t & 63, w = t >> 6;
  int pre = 0, tot = 0;
  for (int b = 0; b < nblk; b++){
    int v = hist[t*nblk + b];
    if (b < blockIdx.x) pre += v;
    tot += v;
  }
  sc[t] = tot; __syncthreads();
  for (int st = 1; st < 256; st <<= 1){
    int a = (t >= st) ? sc[t-st] : 0; __syncthreads();
    sc[t] += a; __syncthreads();
  }
  dbase[t] = sc[t] - tot + pre;
  run[t] = 0;
  for (int u = 0; u < 4; u++){
    wcnt[0][t] = 0; wcnt[1][t] = 0; wcnt[2][t] = 0; wcnt[3][t] = 0;
    __syncthreads();
    int g = blockIdx.x*1024 + u*256 + t;
    unsigned kk = keyin[g]; int id = idxin[g];
    unsigned d = (kk >> shift) & 255u;
    unsigned long long m = ~0ull;
    #pragma unroll
    for (int b = 0; b < 8; b++){
      unsigned long long bal = __ballot((d >> b) & 1u);
      m &= ((d >> b) & 1u) ? bal : ~bal;
    }
    int rnk = __popcll(m & ((1ull << lane) - 1ull));
    if (rnk == 0) wcnt[w][d] = __popcll(m);
    __syncthreads();
    int off2 = run[d] + rnk;
    for (int w2 = 0; w2 < w; w2++) off2 += wcnt[w2][d];
    int pos = dbase[d] + off2;
    keyout[pos] = kk; idxout[pos] = id;
    __syncthreads();
    run[t] += wcnt[0][t] + wcnt[1][t] + wcnt[2][t] + wcnt[3][t];
    __syncthreads();
  }
}

// merged select + gather-scale
__global__ void k_select_gather(const int* __restrict__ idxs, const float* __restrict__ x,
                                const float* __restrict__ score, int* __restrict__ perm,
                                int* __restrict__ mapv, float* __restrict__ xk, int n, int k){
  int t = blockIdx.x*blockDim.x + threadIdx.x;
  if (t < n){
    int i = idxs[t];
    mapv[i] = (t < k) ? t : -1;
    if (t < k) perm[t] = i;
  }
  if (t < k*64){
    int r = t >> 6, f = t & 63;
    int i = idxs[r];
    xk[t] = x[i*64+f]*score[i];
  }
}

extern "C" void kernel_launch(void* const* d_in, const int* in_sizes, int n_in,
                              void* d_out, int out_size, void* d_ws, size_t ws_size,
                              hipStream_t stream) {
  const float* x_in = (const float*)d_in[0];
  const int* ei = (const int*)d_in[1];
  const int* src0 = ei;
  const int* dst0 = ei + NE;
  const float* W_d[4] = {(const float*)d_in[2],(const float*)d_in[5],(const float*)d_in[8],(const float*)d_in[11]};
  const float* g_d[4] = {(const float*)d_in[3],(const float*)d_in[6],(const float*)d_in[9],(const float*)d_in[12]};
  const float* b_d[4] = {(const float*)d_in[4],(const float*)d_in[7],(const float*)d_in[10],(const float*)d_in[13]};
  const float* pw[3]  = {(const float*)d_in[14],(const float*)d_in[15],(const float*)d_in[16]};
  const float* W_u[2] = {(const float*)d_in[17],(const float*)d_in[20]};
  const float* g_u[2] = {(const float*)d_in[18],(const float*)d_in[21]};
  const float* b_u[2] = {(const float*)d_in[19],(const float*)d_in[22]};
  const float* W_out  = (const float*)d_in[23];
  float* out = (float*)d_out;

  float* base = (float*)d_ws;
  size_t off = 0;
  auto alloc = [&](size_t nf){ float* p = base + off; off += nf; return p; };
  float* x0 = alloc(5120000);
  float* x1 = alloc(2560000);
  float* x2 = alloc(1280000);
  float* x3 = alloc(640000);
  float* A  = alloc(2560000);
  float* h3 = alloc(240000);           // gathered 3-wide rows for first conv
  int* col0 = (int*)alloc(NE);
  int* col1 = (int*)alloc(NE);
  int* col2 = (int*)alloc(NE);
  int* col3 = (int*)alloc(NE);
  int* ek1 = (int*)alloc(NE);
  int* ev1 = (int*)alloc(NE);
  int* ek2 = (int*)alloc(NE);
  int* ev2 = (int*)alloc(NE);
  int* rp0 = (int*)alloc(80001);
  int* rp1 = (int*)alloc(40001);
  int* rp2 = (int*)alloc(20001);
  int* rp3 = (int*)alloc(10001);
  int* indeg  = (int*)alloc(NN0);
  float* dinv0  = alloc(NN0);
  float* dinv0f = alloc(NN0);
  float* dinv1  = alloc(40000);
  float* dinv2  = alloc(20000);
  float* dinv3  = alloc(10000);
  float* score = alloc(NN0);
  int* mapv = (int*)alloc(NN0);
  int* p0 = (int*)alloc(40000);
  int* p1 = (int*)alloc(20000);
  int* p2 = (int*)alloc(10000);
  float* stats = alloc(128);
  float* part  = alloc(MMB_GRID*128);
  unsigned* keyA = (unsigned*)alloc(81920);
  unsigned* keyB = (unsigned*)alloc(81920);
  int* idxA = (int*)alloc(81920);
  int* idxB = (int*)alloc(81920);
  int* hist = (int*)alloc(81920);
  int* ehist = (int*)alloc(64*ENB);
  int* bsum = (int*)alloc(256);
  (void)ws_size; (void)in_sizes; (void)n_in; (void)out_size;

  const int B = 256;

  auto scan_flat = [&](int* data, int n2){
    int nb = cdiv(n2, 2048);
    k_scan_part    <<<nb, 256, 0, stream>>>(data, bsum, n2);
    k_scan_fin_flat<<<nb, 256, 0, stream>>>(data, bsum, nb, n2);
  };
  auto scan_csr = [&](const int* indeg_, int* rp, float* dv, int n2){
    int nb = cdiv(n2, 2048);
    k_scan_part  <<<nb, 256, 0, stream>>>(indeg_, bsum, n2);
    k_scan_fin_rp<<<nb, 256, 0, stream>>>(indeg_, bsum, nb, rp, dv, n2);
  };

  auto conv = [&](const float* xin, const float* W, int n,
                  const int* rp, const int* col, const float* dv, float* dstb){
    k_conv64<<<MMB_GRID, B, 0, stream>>>(rp, col, dv, xin, W, dstb, part, n);
    k_stats_reduce<<<128, 64, 0, stream>>>(part, stats);
  };

  auto pool = [&](float* xb, const float* g, const float* bt, const float* w,
                  int n, int k, int* pm, float* xk){
    int nblk = cdiv(n, 1024), P = nblk*1024;
    k_bnrelu_score<<<1024, B, 0, stream>>>(xb, stats, g, bt, w, score, keyA, idxA, n, P);
    unsigned* ka = keyA; int* ia = idxA; unsigned* kb = keyB; int* ib = idxB;
    for (int pass = 0; pass < 4; pass++){
      k_radix_hist   <<<nblk, 256, 0, stream>>>(ka, hist, pass*8, nblk);
      k_radix_scatter<<<nblk, 256, 0, stream>>>(ka, ia, kb, ib, hist, pass*8, nblk);
      std::swap(ka, kb); std::swap(ia, ib);
    }
    k_select_gather<<<cdiv(k*64,B), B, 0, stream>>>(ia, xb, score, pm, mapv, xk, n, k);
  };

  auto csr_mapped = [&](const int* rp_p, const int* col_p, int np, int nc,
                        int* rp_c, int* col_c, float* dv){
    k_hist_mapped<<<cdiv(np,B), B, 0, stream>>>(rp_p, col_p, mapv, indeg, np);
    scan_csr(indeg, rp_c, dv, nc);
    k_scatter_mapped<<<cdiv(np,B), B, 0, stream>>>(rp_p, col_p, mapv, rp_c, col_c, np);
  };

  // ---- level-0 CSR: 3-pass 6-bit LSD radix sort of edges by dst ----
  k_ehist6   <<<ENB, B, 0, stream>>>(dst0, ehist, 0);
  scan_flat(ehist, 64*ENB);
  k_escatter6<<<ENB, B, 0, stream>>>(dst0, src0, ek1, ev1, ehist, 0);
  k_ehist6   <<<ENB, B, 0, stream>>>(ek1, ehist, 6);
  scan_flat(ehist, 64*ENB);
  k_escatter6<<<ENB, B, 0, stream>>>(ek1, ev1, ek2, ev2, ehist, 6);
  k_ehist6   <<<ENB, B, 0, stream>>>(ek2, ehist, 12);
  scan_flat(ehist, 64*ENB);
  k_escatter6<<<ENB, B, 0, stream>>>(ek2, ev2, ek1, col0, ehist, 12);
  k_rp_search<<<cdiv(NN0,B), B, 0, stream>>>(ek1, rp0, dinv0, dinv0f, NN0);

  // ---- down path ----
  k_gather3   <<<cdiv(NN0,B), B, 0, stream>>>(rp0, col0, dinv0, x_in, h3, NN0);
  k_matmul_bn3<<<MMB_GRID, B, 0, stream>>>(h3, W_d[0], x0, part, NN0);
  k_stats_reduce<<<128, 64, 0, stream>>>(part, stats);
  pool(x0, g_d[0], b_d[0], pw[0], NN0, 40000, p0, A);
  csr_mapped(rp0, col0, NN0, 40000, rp1, col1, dinv1);

  conv(A, W_d[1], 40000, rp1, col1, dinv1, x1);
  pool(x1, g_d[1], b_d[1], pw[1], 40000, 20000, p1, A);
  csr_mapped(rp1, col1, 40000, 20000, rp2, col2, dinv2);

  conv(A, W_d[2], 20000, rp2, col2, dinv2, x2);
  pool(x2, g_d[2], b_d[2], pw[2], 20000, 10000, p2, A);
  csr_mapped(rp2, col2, 20000, 10000, rp3, col3, dinv3);

  conv(A, W_d[3], 10000, rp3, col3, dinv3, x3);

  // ---- up path (BN+ReLU fused into the skip-connection scatter-add) ----
  k_bnrelu_scatter<<<cdiv(10000*64,B), B, 0, stream>>>(x3, stats, g_d[3], b_d[3], p2, x2, 10000);
  conv(x2, W_u[0], 20000, rp2, col2, dinv2, A);
  k_bnrelu_scatter<<<cdiv(20000*64,B), B, 0, stream>>>(A, stats, g_u[0], b_u[0], p1, x1, 20000);
  conv(x1, W_u[1], 40000, rp1, col1, dinv1, A);
  k_bnrelu_scatter<<<cdiv(40000*64,B), B, 0, stream>>>(A, stats, g_u[1], b_u[1], p0, x0, 40000);

  // ---- final conv (fill = 1.0) fused with sigmoid ----
  float* h1 = score;  // reuse
  k_matvec<<<512, B, 0, stream>>>(x0, W_out, h1, NN0);
  k_gather_sig<<<cdiv(NN0,B), B, 0, stream>>>(rp0, col0, dinv0f, h1, out, NN0);
}

// Round 16
// 741.529 us; speedup vs baseline: 3.4750x; 1.0018x over previous
//
#include <hip/hip_runtime.h>
#include <cstdint>
#include <utility>

#define NN0 80000
#define NE 1280000
#define MMB_GRID 2048
#define EB 2048          // elems per block in edge sort (NE/EB = 625 exact)
#define ENB 625

static inline int cdiv(int a, int b){ return (a+b-1)/b; }

// ---- FUSED conv: gather (x-space) + matmul [64,64] + BN partials ----
__global__ void k_conv64(const int* __restrict__ rp, const int* __restrict__ col,
                         const float* __restrict__ dinv, const float* __restrict__ x,
                         const float* __restrict__ W, float* __restrict__ out,
                         float* __restrict__ part, int n){
  __shared__ float yl[4][64];
  __shared__ float ls[64], lq[64];
  int lane = threadIdx.x & 63, w = threadIdx.x >> 6;
  if (threadIdx.x < 64){ ls[threadIdx.x] = 0.f; lq[threadIdx.x] = 0.f; }
  __syncthreads();
  float sa = 0.f, sq = 0.f;
  int wid = blockIdx.x*4 + w, nw = gridDim.x*4;
  for (int i = wid; i < n; i += nw){
    int beg = rp[i], end = rp[i+1];
    float di = dinv[i];
    float y = 0.f;
    int j = beg;
    for (; j + 4 <= end; j += 4){
      int s0 = col[j], s1 = col[j+1], s2 = col[j+2], s3 = col[j+3];
      float y0 = dinv[s0]*x[s0*64+lane];
      float y1 = dinv[s1]*x[s1*64+lane];
      float y2 = dinv[s2]*x[s2*64+lane];
      float y3 = dinv[s3]*x[s3*64+lane];
      y += (y0+y1) + (y2+y3);
    }
    for (; j < end; j++){ int s = col[j]; y += dinv[s]*x[s*64+lane]; }
    y = di*y + 2.f*di*di*x[i*64+lane];
    yl[w][lane] = y;
    float acc = 0.f;
    #pragma unroll
    for (int k2 = 0; k2 < 64; k2++)
      acc += yl[w][k2]*W[k2*64+lane];
    out[i*64+lane] = acc;
    sa += acc; sq += acc*acc;
  }
  atomicAdd(&ls[lane], sa); atomicAdd(&lq[lane], sq);
  __syncthreads();
  if (threadIdx.x < 128)
    part[blockIdx.x*128 + threadIdx.x] =
      (threadIdx.x < 64) ? ls[threadIdx.x] : lq[threadIdx.x-64];
}

// FUSED first conv (Fin=3): wave per node, lanes cooperate on edges,
// butterfly-reduce 3 sums, then each lane computes its output channel.
__global__ void k_conv3(const int* __restrict__ rp, const int* __restrict__ col,
                        const float* __restrict__ dinv, const float* __restrict__ x,
                        const float* __restrict__ W, float* __restrict__ out,
                        float* __restrict__ part, int n){
  __shared__ float ls[64], lq[64];
  int lane = threadIdx.x & 63, w = threadIdx.x >> 6;
  if (threadIdx.x < 64){ ls[threadIdx.x] = 0.f; lq[threadIdx.x] = 0.f; }
  __syncthreads();
  float wf0 = W[lane], wf1 = W[64+lane], wf2 = W[128+lane];
  float sa = 0.f, sq = 0.f;
  int wid = blockIdx.x*4 + w, nw = gridDim.x*4;
  for (int i = wid; i < n; i += nw){
    int beg = rp[i], end = rp[i+1];
    float a0 = 0.f, a1 = 0.f, a2 = 0.f;
    for (int j = beg + lane; j < end; j += 64){
      int s2 = col[j];
      float ds = dinv[s2];
      a0 += ds*x[s2*3+0]; a1 += ds*x[s2*3+1]; a2 += ds*x[s2*3+2];
    }
    for (int o = 32; o > 0; o >>= 1){
      a0 += __shfl_xor(a0, o); a1 += __shfl_xor(a1, o); a2 += __shfl_xor(a2, o);
    }
    float di = dinv[i];
    float sl = 2.f*di*di;
    a0 = di*a0 + sl*x[i*3+0];
    a1 = di*a1 + sl*x[i*3+1];
    a2 = di*a2 + sl*x[i*3+2];
    float s = a0*wf0 + a1*wf1 + a2*wf2;
    out[i*64+lane] = s; sa += s; sq += s*s;
  }
  atomicAdd(&ls[lane], sa); atomicAdd(&lq[lane], sq);
  __syncthreads();
  if (threadIdx.x < 128)
    part[blockIdx.x*128 + threadIdx.x] =
      (threadIdx.x < 64) ? ls[threadIdx.x] : lq[threadIdx.x-64];
}

__global__ void k_stats_reduce(const float* __restrict__ part, float* __restrict__ stats){
  int c = blockIdx.x, lane = threadIdx.x;
  float s = 0.f;
  for (int b = lane; b < MMB_GRID; b += 64) s += part[b*128 + c];
  for (int o = 32; o > 0; o >>= 1) s += __shfl_xor(s, o);
  if (lane == 0) stats[c] = s;
}

__global__ void k_matvec(const float* __restrict__ x, const float* __restrict__ W,
                         float* __restrict__ h1, int n){
  int lane = threadIdx.x & 63, w = threadIdx.x >> 6;
  int wid = blockIdx.x*4 + w, nw = gridDim.x*4;
  float wv = W[lane];
  for (int i = wid; i < n; i += nw){
    float v = x[i*64+lane]*wv;
    for (int o = 32; o > 0; o >>= 1) v += __shfl_xor(v, o);
    if (lane == 0) h1[i] = v;
  }
}

// ---- edge radix sort by dst: 3 stable passes of 6 bits (dst < 2^18) ----
__global__ void k_ehist6(const int* __restrict__ key, int* __restrict__ hist, int shift){
  __shared__ int lh[64];
  if (threadIdx.x < 64) lh[threadIdx.x] = 0;
  __syncthreads();
  int base = blockIdx.x*EB + threadIdx.x;
  #pragma unroll
  for (int u = 0; u < 8; u++)
    atomicAdd(&lh[(key[base + u*256] >> shift) & 63], 1);
  __syncthreads();
  if (threadIdx.x < 64) hist[threadIdx.x*ENB + blockIdx.x] = lh[threadIdx.x];
}

__global__ void k_escatter6(const int* __restrict__ keyin, const int* __restrict__ valin,
                            int* __restrict__ keyout, int* __restrict__ valout,
                            const int* __restrict__ hist, int shift){
  __shared__ int dbase[64], run[64], wcnt[4][64];
  int t = threadIdx.x, lane = t & 63, w = t >> 6;
  if (t < 64){ dbase[t] = hist[t*ENB + blockIdx.x]; run[t] = 0; }
  __syncthreads();
  for (int u = 0; u < 8; u++){
    if (t < 64){ wcnt[0][t]=0; wcnt[1][t]=0; wcnt[2][t]=0; wcnt[3][t]=0; }
    __syncthreads();
    int g = blockIdx.x*EB + u*256 + t;
    int kk = keyin[g], vv = valin[g];
    int d = (kk >> shift) & 63;
    unsigned long long m = ~0ull;
    #pragma unroll
    for (int b = 0; b < 6; b++){
      unsigned long long bal = __ballot((d >> b) & 1);
      m &= ((d >> b) & 1) ? bal : ~bal;
    }
    int rnk = __popcll(m & ((1ull << lane) - 1ull));
    if (rnk == 0) wcnt[w][d] = __popcll(m);
    __syncthreads();
    int off2 = run[d] + rnk;
    for (int w2 = 0; w2 < w; w2++) off2 += wcnt[w2][d];
    int pos = dbase[d] + off2;
    keyout[pos] = kk; valout[pos] = vv;
    __syncthreads();
    if (t < 64) run[t] += wcnt[0][t] + wcnt[1][t] + wcnt[2][t] + wcnt[3][t];
    __syncthreads();
  }
}

// rp + dinv from sorted dst keys via binary search (one thread per node)
__global__ void k_rp_search(const int* __restrict__ skey, int* __restrict__ rp,
                            float* __restrict__ dinvA, float* __restrict__ dinvB, int n){
  int i = blockIdx.x*blockDim.x + threadIdx.x;
  if (i >= n) return;
  int lo = 0, hi = NE;
  while (lo < hi){ int mid = (lo+hi)>>1; if (skey[mid] < i) lo = mid+1; else hi = mid; }
  int a = lo;
  lo = a; hi = NE;
  while (lo < hi){ int mid = (lo+hi)>>1; if (skey[mid] < i+1) lo = mid+1; else hi = mid; }
  int b2 = lo;
  rp[i] = a;
  if (i == n-1) rp[n] = NE;
  float deg = (float)(b2 - a);
  dinvA[i] = 1.0f/sqrtf(deg + 2.f);
  dinvB[i] = 1.0f/sqrtf(deg + 1.f);
}

// ---- parallel exclusive scan (2048 elems/block) ----
__global__ void k_scan_part(const int* __restrict__ in, int* __restrict__ bsum, int n){
  __shared__ int ws[256];
  int base = blockIdx.x*2048 + threadIdx.x*8;
  int s = 0;
  #pragma unroll
  for (int u = 0; u < 8; u++){ int i = base+u; if (i < n) s += in[i]; }
  ws[threadIdx.x] = s; __syncthreads();
  for (int st = 128; st > 0; st >>= 1){
    if (threadIdx.x < st) ws[threadIdx.x] += ws[threadIdx.x+st];
    __syncthreads();
  }
  if (threadIdx.x == 0) bsum[blockIdx.x] = ws[0];
}

// final scan stage for CSR: rp[0..n] + fused dinv (fill=2)
__global__ void k_scan_fin_rp(const int* __restrict__ in, const int* __restrict__ bsum, int nb,
                              int* __restrict__ rp, float* __restrict__ dinvA, int n){
  __shared__ int bws[256]; __shared__ int ws[256];
  int t = threadIdx.x;
  bws[t] = (t < nb) ? bsum[t] : 0; __syncthreads();
  for (int st = 1; st < 256; st <<= 1){
    int a = (t >= st) ? bws[t-st] : 0; __syncthreads();
    bws[t] += a; __syncthreads();
  }
  int blockoff = (blockIdx.x == 0) ? 0 : bws[blockIdx.x-1];
  int base = blockIdx.x*2048 + t*8;
  int v[8]; int s = 0;
  #pragma unroll
  for (int u = 0; u < 8; u++){ int i = base+u; v[u] = (i < n) ? in[i] : 0; s += v[u]; }
  ws[t] = s; __syncthreads();
  for (int st = 1; st < 256; st <<= 1){
    int a = (t >= st) ? ws[t-st] : 0; __syncthreads();
    ws[t] += a; __syncthreads();
  }
  int off = blockoff + ws[t] - s;
  #pragma unroll
  for (int u = 0; u < 8; u++){
    int i = base+u;
    if (i < n){
      rp[i] = off; off += v[u];
      dinvA[i] = 1.0f/sqrtf((float)v[u] + 2.f);
      if (i == n-1) rp[n] = off;
    }
  }
}

// final scan stage, in-place flat (edge-sort hist)
__global__ void k_scan_fin_flat(int* __restrict__ data, const int* __restrict__ bsum, int nb, int n){
  __shared__ int bws[256]; __shared__ int ws[256];
  int t = threadIdx.x;
  bws[t] = (t < nb) ? bsum[t] : 0; __syncthreads();
  for (int st = 1; st < 256; st <<= 1){
    int a = (t >= st) ? bws[t-st] : 0; __syncthreads();
    bws[t] += a; __syncthreads();
  }
  int blockoff = (blockIdx.x == 0) ? 0 : bws[blockIdx.x-1];
  int base = blockIdx.x*2048 + t*8;
  int v[8]; int s = 0;
  #pragma unroll
  for (int u = 0; u < 8; u++){ int i = base+u; v[u] = (i < n) ? data[i] : 0; s += v[u]; }
  ws[t] = s; __syncthreads();
  for (int st = 1; st < 256; st <<= 1){
    int a = (t >= st) ? ws[t-st] : 0; __syncthreads();
    ws[t] += a; __syncthreads();
  }
  int off = blockoff + ws[t] - s;
  #pragma unroll
  for (int u = 0; u < 8; u++){
    int i = base+u;
    if (i < n){ data[i] = off; off += v[u]; }
  }
}

// ---- CSR for pooled level from parent CSR + injective mapping ----
__global__ void k_hist_mapped(const int* __restrict__ rp_p, const int* __restrict__ col_p,
                              const int* __restrict__ mapv, int* __restrict__ indeg, int np){
  int d = blockIdx.x*blockDim.x + threadIdx.x;
  if (d >= np) return;
  int md = mapv[d];
  if (md < 0) return;
  int c = 0, e = rp_p[d+1];
  int j = rp_p[d];
  for (; j + 4 <= e; j += 4){
    int c0 = (mapv[col_p[j]]   >= 0);
    int c1 = (mapv[col_p[j+1]] >= 0);
    int c2 = (mapv[col_p[j+2]] >= 0);
    int c3 = (mapv[col_p[j+3]] >= 0);
    c += (c0+c1) + (c2+c3);
  }
  for (; j < e; j++) if (mapv[col_p[j]] >= 0) c++;
  indeg[md] = c;
}
__global__ void k_scatter_mapped(const int* __restrict__ rp_p, const int* __restrict__ col_p,
                                 const int* __restrict__ mapv, const int* __restrict__ rp_c,
                                 int* __restrict__ col_c, int np){
  int d = blockIdx.x*blockDim.x + threadIdx.x;
  if (d >= np) return;
  int md = mapv[d];
  if (md < 0) return;
  int pos = rp_c[md], e = rp_p[d+1];
  int j = rp_p[d];
  for (; j + 4 <= e; j += 4){
    int m0 = mapv[col_p[j]], m1 = mapv[col_p[j+1]];
    int m2 = mapv[col_p[j+2]], m3 = mapv[col_p[j+3]];
    if (m0 >= 0) col_c[pos++] = m0;
    if (m1 >= 0) col_c[pos++] = m1;
    if (m2 >= 0) col_c[pos++] = m2;
    if (m3 >= 0) col_c[pos++] = m3;
  }
  for (; j < e; j++){
    int ms = mapv[col_p[j]];
    if (ms >= 0) col_c[pos++] = ms;
  }
}

// final conv (Fout=1, fill=1) fused with sigmoid; 4-way unrolled
__global__ void k_gather_sig(const int* __restrict__ rp, const int* __restrict__ col,
                             const float* __restrict__ dinv, const float* __restrict__ h1,
                             float* __restrict__ out, int n){
  int i = blockIdx.x*blockDim.x + threadIdx.x;
  if (i >= n) return;
  int beg = rp[i], end = rp[i+1];
  float di = dinv[i];
  float acc = 0.f;
  int j = beg;
  for (; j + 4 <= end; j += 4){
    int s0 = col[j], s1 = col[j+1], s2 = col[j+2], s3 = col[j+3];
    float v0 = dinv[s0]*h1[s0];
    float v1 = dinv[s1]*h1[s1];
    float v2 = dinv[s2]*h1[s2];
    float v3 = dinv[s3]*h1[s3];
    acc += (v0+v1) + (v2+v3);
  }
  for (; j < end; j++) acc += dinv[col[j]]*h1[col[j]];
  float v = di*acc + di*di*h1[i];
  out[i] = 1.f/(1.f+expf(-v));
}

// FUSED BN+ReLU + scatter-add into residual (up-path skip connections)
__global__ void k_bnrelu_scatter(const float* __restrict__ x, const float* __restrict__ stats,
                                 const float* __restrict__ gamma, const float* __restrict__ beta,
                                 const int* __restrict__ perm, float* __restrict__ res, int n){
  int t = blockIdx.x*blockDim.x + threadIdx.x;
  if (t >= n*64) return;
  int r = t >> 6, f = t & 63;
  float inv_n = 1.0f/(float)n;
  float mu = stats[f]*inv_n;
  float var = stats[64+f]*inv_n - mu*mu;
  float v = gamma[f]*(x[t]-mu)*(1.0f/sqrtf(var+1e-5f)) + beta[f];
  res[perm[r]*64+f] += fmaxf(v, 0.f);
}

// fused BN+ReLU (in-place) + pool score + radix init; wave-per-row
__global__ void k_bnrelu_score(float* __restrict__ x, const float* __restrict__ stats,
                               const float* __restrict__ gamma, const float* __restrict__ beta,
                               const float* __restrict__ pw,
                               float* __restrict__ score, unsigned* __restrict__ key,
                               int* __restrict__ idx, int n, int P){
  int lane = threadIdx.x & 63, w = threadIdx.x >> 6;
  int wid = blockIdx.x*4 + w, nw = gridDim.x*4;
  float inv_n = 1.f/(float)n;
  float mu = stats[lane]*inv_n;
  float var = stats[64+lane]*inv_n - mu*mu;
  float gs = gamma[lane]*(1.f/sqrtf(var+1e-5f));
  float bt = beta[lane];
  float pv = pw[lane];
  float q = pv*pv;
  for (int o = 32; o > 0; o >>= 1) q += __shfl_xor(q, o);
  float qn = 1.f/sqrtf(q);
  for (int i = wid; i < n; i += nw){
    float v = fmaxf(gs*(x[i*64+lane]-mu)+bt, 0.f);
    x[i*64+lane] = v;
    float s = v*pv;
    for (int o = 32; o > 0; o >>= 1) s += __shfl_xor(s, o);
    if (lane == 0){
      float sc = fmaxf(s*qn, 0.f);
      score[i] = sc; key[i] = ~__float_as_uint(sc); idx[i] = i;
    }
  }
  for (int g = n + wid; g < P; g += nw)
    if (lane == 0){ key[g] = 0xFFFFFFFFu; idx[g] = 0; }
}

// ---- score radix sort: 2 kernels/pass, 1024 elems/block ----
__global__ void k_radix_hist(const unsigned* __restrict__ key, int* __restrict__ hist,
                             int shift, int nblk){
  __shared__ int lh[256];
  lh[threadIdx.x] = 0; __syncthreads();
  int base = blockIdx.x*1024 + threadIdx.x;
  #pragma unroll
  for (int u = 0; u < 4; u++){
    unsigned d = (key[base + u*256] >> shift) & 255u;
    atomicAdd(&lh[d], 1);
  }
  __syncthreads();
  hist[threadIdx.x*nblk + blockIdx.x] = lh[threadIdx.x];
}

__global__ void k_radix_scatter(const unsigned* __restrict__ keyin, const int* __restrict__ idxin,
                                unsigned* __restrict__ keyout, int* __restrict__ idxout,
                                const int* __restrict__ hist, int shift, int nblk){
  __shared__ int dbase[256], run[256], sc[256];
  __shared__ int wcnt[4][256];
  int t = threadIdx.x, lane = t & 63, w = t >> 6;
  int pre = 0, tot = 0;
  for (int b = 0; b < nblk; b++){
    int v = hist[t*nblk + b];
    if (b < blockIdx.x) pre += v;
    tot += v;
  }
  sc[t] = tot; __syncthreads();
  for (int st = 1; st < 256; st <<= 1){
    int a = (t >= st) ? sc[t-st] : 0; __syncthreads();
    sc[t] += a; __syncthreads();
  }
  dbase[t] = sc[t] - tot + pre;
  run[t] = 0;
  for (int u = 0; u < 4; u++){
    wcnt[0][t] = 0; wcnt[1][t] = 0; wcnt[2][t] = 0; wcnt[3][t] = 0;
    __syncthreads();
    int g = blockIdx.x*1024 + u*256 + t;
    unsigned kk = keyin[g]; int id = idxin[g];
    unsigned d = (kk >> shift) & 255u;
    unsigned long long m = ~0ull;
    #pragma unroll
    for (int b = 0; b < 8; b++){
      unsigned long long bal = __ballot((d >> b) & 1u);
      m &= ((d >> b) & 1u) ? bal : ~bal;
    }
    int rnk = __popcll(m & ((1ull << lane) - 1ull));
    if (rnk == 0) wcnt[w][d] = __popcll(m);
    __syncthreads();
    int off2 = run[d] + rnk;
    for (int w2 = 0; w2 < w; w2++) off2 += wcnt[w2][d];
    int pos = dbase[d] + off2;
    keyout[pos] = kk; idxout[pos] = id;
    __syncthreads();
    run[t] += wcnt[0][t] + wcnt[1][t] + wcnt[2][t] + wcnt[3][t];
    __syncthreads();
  }
}

// merged select + gather-scale
__global__ void k_select_gather(const int* __restrict__ idxs, const float* __restrict__ x,
                                const float* __restrict__ score, int* __restrict__ perm,
                                int* __restrict__ mapv, float* __restrict__ xk, int n, int k){
  int t = blockIdx.x*blockDim.x + threadIdx.x;
  if (t < n){
    int i = idxs[t];
    mapv[i] = (t < k) ? t : -1;
    if (t < k) perm[t] = i;
  }
  if (t < k*64){
    int r = t >> 6, f = t & 63;
    int i = idxs[r];
    xk[t] = x[i*64+f]*score[i];
  }
}

extern "C" void kernel_launch(void* const* d_in, const int* in_sizes, int n_in,
                              void* d_out, int out_size, void* d_ws, size_t ws_size,
                              hipStream_t stream) {
  const float* x_in = (const float*)d_in[0];
  const int* ei = (const int*)d_in[1];
  const int* src0 = ei;
  const int* dst0 = ei + NE;
  const float* W_d[4] = {(const float*)d_in[2],(const float*)d_in[5],(const float*)d_in[8],(const float*)d_in[11]};
  const float* g_d[4] = {(const float*)d_in[3],(const float*)d_in[6],(const float*)d_in[9],(const float*)d_in[12]};
  const float* b_d[4] = {(const float*)d_in[4],(const float*)d_in[7],(const float*)d_in[10],(const float*)d_in[13]};
  const float* pw[3]  = {(const float*)d_in[14],(const float*)d_in[15],(const float*)d_in[16]};
  const float* W_u[2] = {(const float*)d_in[17],(const float*)d_in[20]};
  const float* g_u[2] = {(const float*)d_in[18],(const float*)d_in[21]};
  const float* b_u[2] = {(const float*)d_in[19],(const float*)d_in[22]};
  const float* W_out  = (const float*)d_in[23];
  float* out = (float*)d_out;

  float* base = (float*)d_ws;
  size_t off = 0;
  auto alloc = [&](size_t nf){ float* p = base + off; off += nf; return p; };
  float* x0 = alloc(5120000);
  float* x1 = alloc(2560000);
  float* x2 = alloc(1280000);
  float* x3 = alloc(640000);
  float* A  = alloc(2560000);
  int* col0 = (int*)alloc(NE);
  int* col1 = (int*)alloc(NE);
  int* col2 = (int*)alloc(NE);
  int* col3 = (int*)alloc(NE);
  int* ek1 = (int*)alloc(NE);
  int* ev1 = (int*)alloc(NE);
  int* ek2 = (int*)alloc(NE);
  int* ev2 = (int*)alloc(NE);
  int* rp0 = (int*)alloc(80001);
  int* rp1 = (int*)alloc(40001);
  int* rp2 = (int*)alloc(20001);
  int* rp3 = (int*)alloc(10001);
  int* indeg  = (int*)alloc(NN0);
  float* dinv0  = alloc(NN0);
  float* dinv0f = alloc(NN0);
  float* dinv1  = alloc(40000);
  float* dinv2  = alloc(20000);
  float* dinv3  = alloc(10000);
  float* score = alloc(NN0);
  int* mapv = (int*)alloc(NN0);
  int* p0 = (int*)alloc(40000);
  int* p1 = (int*)alloc(20000);
  int* p2 = (int*)alloc(10000);
  float* stats = alloc(128);
  float* part  = alloc(MMB_GRID*128);
  unsigned* keyA = (unsigned*)alloc(81920);
  unsigned* keyB = (unsigned*)alloc(81920);
  int* idxA = (int*)alloc(81920);
  int* idxB = (int*)alloc(81920);
  int* hist = (int*)alloc(81920);
  int* ehist = (int*)alloc(64*ENB);
  int* bsum = (int*)alloc(256);
  (void)ws_size; (void)in_sizes; (void)n_in; (void)out_size;

  const int B = 256;

  auto scan_flat = [&](int* data, int n2){
    int nb = cdiv(n2, 2048);
    k_scan_part    <<<nb, 256, 0, stream>>>(data, bsum, n2);
    k_scan_fin_flat<<<nb, 256, 0, stream>>>(data, bsum, nb, n2);
  };
  auto scan_csr = [&](const int* indeg_, int* rp, float* dv, int n2){
    int nb = cdiv(n2, 2048);
    k_scan_part  <<<nb, 256, 0, stream>>>(indeg_, bsum, n2);
    k_scan_fin_rp<<<nb, 256, 0, stream>>>(indeg_, bsum, nb, rp, dv, n2);
  };

  auto conv = [&](const float* xin, const float* W, int n,
                  const int* rp, const int* col, const float* dv, float* dstb){
    k_conv64<<<MMB_GRID, B, 0, stream>>>(rp, col, dv, xin, W, dstb, part, n);
    k_stats_reduce<<<128, 64, 0, stream>>>(part, stats);
  };

  auto pool = [&](float* xb, const float* g, const float* bt, const float* w,
                  int n, int k, int* pm, float* xk){
    int nblk = cdiv(n, 1024), P = nblk*1024;
    k_bnrelu_score<<<1024, B, 0, stream>>>(xb, stats, g, bt, w, score, keyA, idxA, n, P);
    unsigned* ka = keyA; int* ia = idxA; unsigned* kb = keyB; int* ib = idxB;
    for (int pass = 0; pass < 4; pass++){
      k_radix_hist   <<<nblk, 256, 0, stream>>>(ka, hist, pass*8, nblk);
      k_radix_scatter<<<nblk, 256, 0, stream>>>(ka, ia, kb, ib, hist, pass*8, nblk);
      std::swap(ka, kb); std::swap(ia, ib);
    }
    k_select_gather<<<cdiv(k*64,B), B, 0, stream>>>(ia, xb, score, pm, mapv, xk, n, k);
  };

  auto csr_mapped = [&](const int* rp_p, const int* col_p, int np, int nc,
                        int* rp_c, int* col_c, float* dv){
    k_hist_mapped<<<cdiv(np,B), B, 0, stream>>>(rp_p, col_p, mapv, indeg, np);
    scan_csr(indeg, rp_c, dv, nc);
    k_scatter_mapped<<<cdiv(np,B), B, 0, stream>>>(rp_p, col_p, mapv, rp_c, col_c, np);
  };

  // ---- level-0 CSR: 3-pass 6-bit LSD radix sort of edges by dst ----
  k_ehist6   <<<ENB, B, 0, stream>>>(dst0, ehist, 0);
  scan_flat(ehist, 64*ENB);
  k_escatter6<<<ENB, B, 0, stream>>>(dst0, src0, ek1, ev1, ehist, 0);
  k_ehist6   <<<ENB, B, 0, stream>>>(ek1, ehist, 6);
  scan_flat(ehist, 64*ENB);
  k_escatter6<<<ENB, B, 0, stream>>>(ek1, ev1, ek2, ev2, ehist, 6);
  k_ehist6   <<<ENB, B, 0, stream>>>(ek2, ehist, 12);
  scan_flat(ehist, 64*ENB);
  k_escatter6<<<ENB, B, 0, stream>>>(ek2, ev2, ek1, col0, ehist, 12);
  k_rp_search<<<cdiv(NN0,B), B, 0, stream>>>(ek1, rp0, dinv0, dinv0f, NN0);

  // ---- down path ----
  k_conv3<<<MMB_GRID, B, 0, stream>>>(rp0, col0, dinv0, x_in, W_d[0], x0, part, NN0);
  k_stats_reduce<<<128, 64, 0, stream>>>(part, stats);
  pool(x0, g_d[0], b_d[0], pw[0], NN0, 40000, p0, A);
  csr_mapped(rp0, col0, NN0, 40000, rp1, col1, dinv1);

  conv(A, W_d[1], 40000, rp1, col1, dinv1, x1);
  pool(x1, g_d[1], b_d[1], pw[1], 40000, 20000, p1, A);
  csr_mapped(rp1, col1, 40000, 20000, rp2, col2, dinv2);

  conv(A, W_d[2], 20000, rp2, col2, dinv2, x2);
  pool(x2, g_d[2], b_d[2], pw[2], 20000, 10000, p2, A);
  csr_mapped(rp2, col2, 20000, 10000, rp3, col3, dinv3);

  conv(A, W_d[3], 10000, rp3, col3, dinv3, x3);

  // ---- up path (BN+ReLU fused into the skip-connection scatter-add) ----
  k_bnrelu_scatter<<<cdiv(10000*64,B), B, 0, stream>>>(x3, stats, g_d[3], b_d[3], p2, x2, 10000);
  conv(x2, W_u[0], 20000, rp2, col2, dinv2, A);
  k_bnrelu_scatter<<<cdiv(20000*64,B), B, 0, stream>>>(A, stats, g_u[0], b_u[0], p1, x1, 20000);
  conv(x1, W_u[1], 40000, rp1, col1, dinv1, A);
  k_bnrelu_scatter<<<cdiv(40000*64,B), B, 0, stream>>>(A, stats, g_u[1], b_u[1], p0, x0, 40000);

  // ---- final conv (fill = 1.0) fused with sigmoid ----
  float* h1 = score;  // reuse
  k_matvec<<<512, B, 0, stream>>>(x0, W_out, h1, NN0);
  k_gather_sig<<<cdiv(NN0,B), B, 0, stream>>>(rp0, col0, dinv0f, h1, out, NN0);
}